// Round 2
// baseline (791.749 us; speedup 1.0000x reference)
//
#include <hip/hip_runtime.h>
#include <hip/hip_bf16.h>
#include <stdint.h>

#define D_MODEL 1024
#define NHEADS  16
#define DH      64
#define NBATCH  4
#define SEQLEN  4096
#define MROWS   (NBATCH*SEQLEN)   // 16384
#define EPSV    1e-10f

typedef __hip_bfloat16 bf16;
typedef __attribute__((ext_vector_type(8))) short short8;   // 8 bf16 (4 VGPRs)
typedef __attribute__((ext_vector_type(4))) float f32x4;

struct __align__(8) bf16x4s { bf16 a, b, c, d; };

__device__ __forceinline__ void async_copy16(void* lds, const void* g) {
  __builtin_amdgcn_global_load_lds(
      (const __attribute__((address_space(1))) unsigned int*)(uintptr_t)g,
      (__attribute__((address_space(3))) unsigned int*)(uintptr_t)lds,
      16, 0, 0);
}

// ---------------- f32 -> bf16 conversion (vectorized, exact grid) ----------------
__global__ __launch_bounds__(256)
void cvt_bf16(const float* __restrict__ s, bf16* __restrict__ d) {
  const int i = blockIdx.x * 256 + threadIdx.x;   // grid covers n/4 exactly
  const f32x4 v = ((const f32x4*)s)[i];
  bf16x4s o;
  o.a = __float2bfloat16(v[0]);
  o.b = __float2bfloat16(v[1]);
  o.c = __float2bfloat16(v[2]);
  o.d = __float2bfloat16(v[3]);
  ((bf16x4s*)d)[i] = o;
}

// ---------------- weight transpose + cvt (W[K,N] f32 -> WT[N,K] bf16) ----------------
__global__ void transpose4(const float* __restrict__ s0, const float* __restrict__ s1,
                           const float* __restrict__ s2, const float* __restrict__ s3,
                           bf16* __restrict__ d0, bf16* __restrict__ d1,
                           bf16* __restrict__ d2, bf16* __restrict__ d3) {
  const float* s; bf16* d;
  switch (blockIdx.z) {
    case 0: s = s0; d = d0; break;
    case 1: s = s1; d = d1; break;
    case 2: s = s2; d = d2; break;
    default: s = s3; d = d3; break;
  }
  __shared__ float tile[32][33];
  int x = blockIdx.x*32 + threadIdx.x;
  int y = blockIdx.y*32 + threadIdx.y;
  tile[threadIdx.y][threadIdx.x] = s[(size_t)y*D_MODEL + x];
  __syncthreads();
  int xo = blockIdx.y*32 + threadIdx.x;
  int yo = blockIdx.x*32 + threadIdx.y;
  d[(size_t)yo*D_MODEL + xo] = __float2bfloat16(tile[threadIdx.x][threadIdx.y]);
}

// ---------------- GEMM: C[M,N] = act(A[M,K] @ BT[N,K]^T + bias) ----------------
// 128x128 tile, BK=32, 4 waves x (4x4) 16x16x32 MFMA tiles (verified m97 structure)
__device__ __forceinline__ void storeC(float* p, float v) { *p = v; }
__device__ __forceinline__ void storeC(bf16*  p, float v) { *p = __float2bfloat16(v); }

template<int ACT, typename CT>
__global__ __launch_bounds__(256)
void gemm_bias_act(const bf16* __restrict__ A, const bf16* __restrict__ BT,
                   const float* __restrict__ bias, CT* __restrict__ C,
                   int M, int N, int K) {
  __shared__ __align__(16) short Asm[128*32];
  __shared__ __align__(16) short Bsm[128*32];
  const int tid  = threadIdx.x;
  const int wave = tid >> 6;
  const int lane = tid & 63;
  const int m0 = blockIdx.y * 128;
  const int n0 = blockIdx.x * 128;
  const int wr = wave >> 1, wc = wave & 1;
  const int srow = wave*16 + (lane>>2);   // staging row within 64-row round
  const int scol = (lane&3)*8;            // staging col (8 bf16 = 16 B)
  const int fr   = lane & 15;
  const int quad = lane >> 4;

  f32x4 acc[4][4] = {};

  for (int k0 = 0; k0 < K; k0 += 32) {
    __syncthreads();
    #pragma unroll
    for (int r = 0; r < 2; ++r) {
      const int row = r*64 + srow;
      async_copy16(&Asm[row*32 + scol], A  + (size_t)(m0+row)*K + k0 + scol);
      async_copy16(&Bsm[row*32 + scol], BT + (size_t)(n0+row)*K + k0 + scol);
    }
    __syncthreads();   // compiler emits s_waitcnt vmcnt(0) before s_barrier
    short8 afr[4], bfr[4];
    #pragma unroll
    for (int i = 0; i < 4; ++i) {
      afr[i] = *(const short8*)&Asm[(wr*64 + i*16 + fr)*32 + quad*8];
      bfr[i] = *(const short8*)&Bsm[(wc*64 + i*16 + fr)*32 + quad*8];
    }
    #pragma unroll
    for (int i = 0; i < 4; ++i)
      #pragma unroll
      for (int j = 0; j < 4; ++j)
        acc[i][j] = __builtin_amdgcn_mfma_f32_16x16x32_bf16(afr[i], bfr[j], acc[i][j], 0, 0, 0);
  }

  // epilogue: C/D layout col(n)=lane&15, row(m)=quad*4+reg  [measured m89/m91]
  #pragma unroll
  for (int j = 0; j < 4; ++j) {
    const int gn = n0 + wc*64 + j*16 + fr;
    const float bv = bias[gn];
    #pragma unroll
    for (int i = 0; i < 4; ++i) {
      const int gm = m0 + wr*64 + i*16 + quad*4;
      #pragma unroll
      for (int r2 = 0; r2 < 4; ++r2) {
        float v = acc[i][j][r2] + bv;
        if (ACT) v = (v > 0.f) ? (v + 1.f) : __expf(v);   // elu(x)+1
        storeC(&C[(size_t)(gm + r2)*N + gn], v);
      }
    }
  }
}

// ---------------- KV + K_sum accumulation ----------------
// KV[n][h][m][d] = sum_s K_lin[n,s,h,d] * V[n,s,h,m];  K_sum[n][h][d] = sum_s K_lin
#define KV_SPLIT 8
__global__ __launch_bounds__(256)
void kv_kernel(const bf16* __restrict__ Kl, const bf16* __restrict__ V,
               float* __restrict__ KV, float* __restrict__ Ksum) {
  const int b = blockIdx.x;
  const int split = b % KV_SPLIT;
  const int h = (b / KV_SPLIT) % NHEADS;
  const int n = b / (KV_SPLIT * NHEADS);
  const int tid = threadIdx.x;
  const int S_PER = SEQLEN / KV_SPLIT;   // 512
  const int s0 = split * S_PER;
  __shared__ float Ks[8][64];
  __shared__ float Vs[8][64];
  float acc[4][4] = {};
  float ks[4] = {0.f,0.f,0.f,0.f};
  const int dm = tid & 15;    // m patch
  const int dd = tid >> 4;    // d patch (0..15)

  for (int sc = 0; sc < S_PER; sc += 8) {
    __syncthreads();
    for (int i = tid; i < 8*64; i += 256) {
      const int sr = i >> 6, c = i & 63;
      const size_t base = ((size_t)(n*SEQLEN + s0 + sc + sr))*D_MODEL + h*DH + c;
      Ks[sr][c] = __bfloat162float(Kl[base]);
      Vs[sr][c] = __bfloat162float(V[base]);
    }
    __syncthreads();
    #pragma unroll
    for (int sr = 0; sr < 8; ++sr) {
      float kv4[4], vv4[4];
      #pragma unroll
      for (int x = 0; x < 4; ++x) { kv4[x] = Ks[sr][dd*4+x]; vv4[x] = Vs[sr][dm*4+x]; }
      #pragma unroll
      for (int xm = 0; xm < 4; ++xm)
        #pragma unroll
        for (int xd = 0; xd < 4; ++xd)
          acc[xm][xd] += vv4[xm] * kv4[xd];
      if (dm == 0) {
        #pragma unroll
        for (int x = 0; x < 4; ++x) ks[x] += kv4[x];
      }
    }
  }
  float* kvp = KV + ((size_t)(n*NHEADS + h))*DH*DH;
  #pragma unroll
  for (int xm = 0; xm < 4; ++xm)
    #pragma unroll
    for (int xd = 0; xd < 4; ++xd)
      atomicAdd(&kvp[(dm*4+xm)*DH + dd*4+xd], acc[xm][xd]);
  if (dm == 0) {
    float* ksp = Ksum + (n*NHEADS + h)*DH;
    #pragma unroll
    for (int x = 0; x < 4; ++x) atomicAdd(&ksp[dd*4+x], ks[x]);
  }
}

// ---------------- V_lin = Z * (Q_lin . KV) ----------------
__global__ __launch_bounds__(256)
void vlin_kernel(const bf16* __restrict__ Ql, const float* __restrict__ KV,
                 const float* __restrict__ Ksum, bf16* __restrict__ Vl) {
  const int LCH = 256;
  const int b  = blockIdx.x;
  const int lc = b % (SEQLEN/LCH);
  const int h  = (b / (SEQLEN/LCH)) % NHEADS;
  const int n  = b / ((SEQLEN/LCH)*NHEADS);
  const int tid = threadIdx.x, wave = tid >> 6, lane = tid & 63;
  __shared__ float KVs[64*65];   // padded stride 65 -> conflict-free column reads
  __shared__ float Kss[64];
  const float* kvp = KV + ((size_t)(n*NHEADS + h))*DH*DH;
  for (int i = tid; i < 64*64; i += 256)
    KVs[(i>>6)*65 + (i&63)] = kvp[i];
  if (tid < 64) Kss[tid] = Ksum[(n*NHEADS + h)*DH + tid];
  __syncthreads();

  for (int lo = wave; lo < LCH; lo += 4) {
    const int l = lc*LCH + lo;
    const size_t qbase = ((size_t)(n*SEQLEN + l))*D_MODEL + h*DH;
    const float qv = __bfloat162float(Ql[qbase + lane]);   // lane = d
    float zp = qv * Kss[lane];
    #pragma unroll
    for (int off = 32; off; off >>= 1) zp += __shfl_xor(zp, off, 64);
    const float Z = 1.0f / (zp + EPSV);
    float accv = 0.f;
    #pragma unroll
    for (int d = 0; d < 64; ++d) {
      const float qd = __shfl(qv, d, 64);
      accv += qd * KVs[lane*65 + d];   // lane = m
    }
    Vl[qbase + lane] = __float2bfloat16(accv * Z);
  }
}

// ---------------- launch ----------------
extern "C" void kernel_launch(void* const* d_in, const int* in_sizes, int n_in,
                              void* d_out, int out_size, void* d_ws, size_t ws_size,
                              hipStream_t stream) {
  // Reference dtypes are float32 for ALL tensors.
  const float* q  = (const float*)d_in[0];
  const float* k  = (const float*)d_in[1];
  const float* v  = (const float*)d_in[2];
  const float* Wq = (const float*)d_in[3];
  const float* bq = (const float*)d_in[4];
  const float* Wk = (const float*)d_in[5];
  const float* bk = (const float*)d_in[6];
  const float* Wv = (const float*)d_in[7];
  const float* bv = (const float*)d_in[8];
  const float* Wo = (const float*)d_in[9];
  const float* bo = (const float*)d_in[10];
  float* out = (float*)d_out;

  bf16* WqT = (bf16*)d_ws;
  bf16* WkT = WqT + (size_t)D_MODEL*D_MODEL;
  bf16* WvT = WkT + (size_t)D_MODEL*D_MODEL;
  bf16* WoT = WvT + (size_t)D_MODEL*D_MODEL;
  bf16* Xb  = WoT + (size_t)D_MODEL*D_MODEL;   // 32 MB staging, reused q->k->v
  bf16* Ql  = Xb  + (size_t)MROWS*D_MODEL;
  bf16* Kl  = Ql  + (size_t)MROWS*D_MODEL;
  bf16* Vb  = Kl  + (size_t)MROWS*D_MODEL;
  bf16* Vl  = Kl;                              // reuse: K_lin dead after kv_kernel
  float* KV = (float*)(Vb + (size_t)MROWS*D_MODEL);
  float* Ks = KV + (size_t)NBATCH*NHEADS*DH*DH;

  hipMemsetAsync(KV, 0, ((size_t)NBATCH*NHEADS*DH*DH + NBATCH*NHEADS*DH)*sizeof(float), stream);

  transpose4<<<dim3(32,32,4), dim3(32,32,1), 0, stream>>>(Wq,Wk,Wv,Wo, WqT,WkT,WvT,WoT);

  const int nconv4 = MROWS*D_MODEL/4;          // 4,194,304 -> grid 16384 exact
  dim3 gb(256), gg(D_MODEL/128, MROWS/128);    // (8, 128)

  cvt_bf16<<<nconv4/256, 256, 0, stream>>>(q, Xb);
  gemm_bias_act<1,bf16><<<gg, gb, 0, stream>>>(Xb, WqT, bq, Ql, MROWS, D_MODEL, D_MODEL);
  cvt_bf16<<<nconv4/256, 256, 0, stream>>>(k, Xb);
  gemm_bias_act<1,bf16><<<gg, gb, 0, stream>>>(Xb, WkT, bk, Kl, MROWS, D_MODEL, D_MODEL);
  cvt_bf16<<<nconv4/256, 256, 0, stream>>>(v, Xb);
  gemm_bias_act<0,bf16><<<gg, gb, 0, stream>>>(Xb, WvT, bv, Vb, MROWS, D_MODEL, D_MODEL);

  kv_kernel<<<dim3(NBATCH*NHEADS*KV_SPLIT), dim3(256), 0, stream>>>(Kl, Vb, KV, Ks);
  vlin_kernel<<<dim3(NBATCH*NHEADS*(SEQLEN/256)), dim3(256), 0, stream>>>(Ql, KV, Ks, Vl);

  gemm_bias_act<0,float><<<gg, gb, 0, stream>>>(Vl, WoT, bo, out, MROWS, D_MODEL, D_MODEL);
}

// Round 3
// 590.649 us; speedup vs baseline: 1.3405x; 1.3405x over previous
//
#include <hip/hip_runtime.h>
#include <hip/hip_bf16.h>
#include <stdint.h>

#define D_MODEL 1024
#define NHEADS  16
#define DH      64
#define NBATCH  4
#define SEQLEN  4096
#define MROWS   (NBATCH*SEQLEN)   // 16384
#define EPSV    1e-10f

typedef __hip_bfloat16 bf16;
typedef __attribute__((ext_vector_type(8))) short short8;   // 8 bf16 (4 VGPRs)
typedef __attribute__((ext_vector_type(4))) float f32x4;

struct __align__(8) bf16x4s { bf16 a, b, c, d; };

__device__ __forceinline__ void async_copy16(void* lds, const void* g) {
  __builtin_amdgcn_global_load_lds(
      (const __attribute__((address_space(1))) unsigned int*)(uintptr_t)g,
      (__attribute__((address_space(3))) unsigned int*)(uintptr_t)lds,
      16, 0, 0);
}

__device__ __forceinline__ short f2bf_bits(float v) {
  bf16 b = __float2bfloat16(v);
  short s; __builtin_memcpy(&s, &b, 2); return s;
}

// ---------------- f32 -> bf16 conversion (vectorized, exact grid) ----------------
__global__ __launch_bounds__(256)
void cvt_bf16(const float* __restrict__ s, bf16* __restrict__ d) {
  const int i = blockIdx.x * 256 + threadIdx.x;
  const f32x4 v = ((const f32x4*)s)[i];
  bf16x4s o;
  o.a = __float2bfloat16(v[0]);
  o.b = __float2bfloat16(v[1]);
  o.c = __float2bfloat16(v[2]);
  o.d = __float2bfloat16(v[3]);
  ((bf16x4s*)d)[i] = o;
}

// ---------------- weight transpose + cvt (W[K,N] f32 -> WT[N,K] bf16) ----------------
__global__ void transpose4(const float* __restrict__ s0, const float* __restrict__ s1,
                           const float* __restrict__ s2, const float* __restrict__ s3,
                           bf16* __restrict__ d0, bf16* __restrict__ d1,
                           bf16* __restrict__ d2, bf16* __restrict__ d3) {
  const float* s; bf16* d;
  switch (blockIdx.z) {
    case 0: s = s0; d = d0; break;
    case 1: s = s1; d = d1; break;
    case 2: s = s2; d = d2; break;
    default: s = s3; d = d3; break;
  }
  __shared__ float tile[32][33];
  int x = blockIdx.x*32 + threadIdx.x;
  int y = blockIdx.y*32 + threadIdx.y;
  tile[threadIdx.y][threadIdx.x] = s[(size_t)y*D_MODEL + x];
  __syncthreads();
  int xo = blockIdx.y*32 + threadIdx.x;
  int yo = blockIdx.x*32 + threadIdx.y;
  d[(size_t)yo*D_MODEL + xo] = __float2bfloat16(tile[threadIdx.x][threadIdx.y]);
}

// ---------------- GEMM: C[M,N] = act(A[M,K] @ BT[N,K]^T + bias) ----------------
// 128x128 tile, BK=32, 4 waves x (4x4) 16x16x32 MFMA tiles (verified m97 structure)
__device__ __forceinline__ void storeC(float* p, float v) { *p = v; }
__device__ __forceinline__ void storeC(bf16*  p, float v) { *p = __float2bfloat16(v); }

template<int ACT, typename CT>
__global__ __launch_bounds__(256)
void gemm_bias_act(const bf16* __restrict__ A, const bf16* __restrict__ BT,
                   const float* __restrict__ bias, CT* __restrict__ C,
                   int M, int N, int K) {
  __shared__ __align__(16) short Asm[128*32];
  __shared__ __align__(16) short Bsm[128*32];
  const int tid  = threadIdx.x;
  const int wave = tid >> 6;
  const int lane = tid & 63;
  const int m0 = blockIdx.y * 128;
  const int n0 = blockIdx.x * 128;
  const int wr = wave >> 1, wc = wave & 1;
  const int srow = wave*16 + (lane>>2);
  const int scol = (lane&3)*8;
  const int fr   = lane & 15;
  const int quad = lane >> 4;

  f32x4 acc[4][4] = {};

  for (int k0 = 0; k0 < K; k0 += 32) {
    __syncthreads();
    #pragma unroll
    for (int r = 0; r < 2; ++r) {
      const int row = r*64 + srow;
      async_copy16(&Asm[row*32 + scol], A  + (size_t)(m0+row)*K + k0 + scol);
      async_copy16(&Bsm[row*32 + scol], BT + (size_t)(n0+row)*K + k0 + scol);
    }
    __syncthreads();
    short8 afr[4], bfr[4];
    #pragma unroll
    for (int i = 0; i < 4; ++i) {
      afr[i] = *(const short8*)&Asm[(wr*64 + i*16 + fr)*32 + quad*8];
      bfr[i] = *(const short8*)&Bsm[(wc*64 + i*16 + fr)*32 + quad*8];
    }
    #pragma unroll
    for (int i = 0; i < 4; ++i)
      #pragma unroll
      for (int j = 0; j < 4; ++j)
        acc[i][j] = __builtin_amdgcn_mfma_f32_16x16x32_bf16(afr[i], bfr[j], acc[i][j], 0, 0, 0);
  }

  #pragma unroll
  for (int j = 0; j < 4; ++j) {
    const int gn = n0 + wc*64 + j*16 + fr;
    const float bv = bias[gn];
    #pragma unroll
    for (int i = 0; i < 4; ++i) {
      const int gm = m0 + wr*64 + i*16 + quad*4;
      #pragma unroll
      for (int r2 = 0; r2 < 4; ++r2) {
        float v = acc[i][j][r2] + bv;
        if (ACT) v = (v > 0.f) ? (v + 1.f) : __expf(v);   // elu(x)+1
        storeC(&C[(size_t)(gm + r2)*N + gn], v);
      }
    }
  }
}

// ---------------- KV + K_sum accumulation ----------------
// KV[n][h][m][d] = sum_s K_lin[n,s,h,d] * V[n,s,h,m];  K_sum[n][h][d] = sum_s K_lin
#define KV_SPLIT 8
__global__ __launch_bounds__(256)
void kv_kernel(const bf16* __restrict__ Kl, const bf16* __restrict__ V,
               float* __restrict__ KV, float* __restrict__ Ksum) {
  const int b = blockIdx.x;
  const int split = b % KV_SPLIT;
  const int h = (b / KV_SPLIT) % NHEADS;
  const int n = b / (KV_SPLIT * NHEADS);
  const int tid = threadIdx.x;
  const int S_PER = SEQLEN / KV_SPLIT;   // 512
  const int s0 = split * S_PER;
  __shared__ float Ks[8][64];
  __shared__ float Vs[8][64];
  float acc[4][4] = {};
  float ks[4] = {0.f,0.f,0.f,0.f};
  const int dm = tid & 15;    // m patch
  const int dd = tid >> 4;    // d patch (0..15)
  const int lrow = tid >> 5, lcp = tid & 31;   // staging: 8 rows x 32 pairs

  for (int sc = 0; sc < S_PER; sc += 8) {
    __syncthreads();
    {
      const size_t base = ((size_t)(n*SEQLEN + s0 + sc + lrow))*D_MODEL + h*DH + lcp*2;
      unsigned int ku, vu;
      __builtin_memcpy(&ku, Kl + base, 4);
      __builtin_memcpy(&vu, V  + base, 4);
      float2 kf, vf;
      kf.x = __uint_as_float(ku << 16);  kf.y = __uint_as_float(ku & 0xffff0000u);
      vf.x = __uint_as_float(vu << 16);  vf.y = __uint_as_float(vu & 0xffff0000u);
      *(float2*)&Ks[lrow][lcp*2] = kf;
      *(float2*)&Vs[lrow][lcp*2] = vf;
    }
    __syncthreads();
    #pragma unroll
    for (int sr = 0; sr < 8; ++sr) {
      f32x4 kv4 = *(const f32x4*)&Ks[sr][dd*4];
      f32x4 vv4 = *(const f32x4*)&Vs[sr][dm*4];
      #pragma unroll
      for (int xm = 0; xm < 4; ++xm)
        #pragma unroll
        for (int xd = 0; xd < 4; ++xd)
          acc[xm][xd] += vv4[xm] * kv4[xd];
      if (dm == 0) {
        #pragma unroll
        for (int x = 0; x < 4; ++x) ks[x] += kv4[x];
      }
    }
  }
  float* kvp = KV + ((size_t)(n*NHEADS + h))*DH*DH;
  #pragma unroll
  for (int xm = 0; xm < 4; ++xm)
    #pragma unroll
    for (int xd = 0; xd < 4; ++xd)
      atomicAdd(&kvp[(dm*4+xm)*DH + dd*4+xd], acc[xm][xd]);
  if (dm == 0) {
    float* ksp = Ksum + (n*NHEADS + h)*DH;
    #pragma unroll
    for (int x = 0; x < 4; ++x) atomicAdd(&ksp[dd*4+x], ks[x]);
  }
}

// ---------------- V_lin = Z * (Q_lin . KV)  — MFMA batched GEMM ----------------
// Per (n,h): P[l, 0:64] = Ql @ KV^T (hi/lo split), P[l,128/129] = Ql . Ksum(hi/lo)
// B rows: 0-63 hi(KV[m]), 64-127 lo(KV[m]), 128 hi(Ksum), 129 lo(Ksum), 130-143 zero.
__device__ __forceinline__ int bswz(int row, int d) {   // XOR-swizzled LDS index
  return row*64 + ((((d >> 3) ^ (row & 7)) << 3) | (d & 7));
}

__global__ __launch_bounds__(256)
void vlin_kernel(const bf16* __restrict__ Ql, const float* __restrict__ KV,
                 const float* __restrict__ Ksum, bf16* __restrict__ Vl) {
  const int lc = blockIdx.x;            // l-chunk of 128 rows (32 total)
  const int nh = blockIdx.y;            // n*NHEADS + h
  const int h = nh & (NHEADS-1), n = nh >> 4;
  const int tid = threadIdx.x, wave = tid >> 6, lane = tid & 63;
  const int fr = lane & 15, quad = lane >> 4;

  __shared__ __align__(16) short Bs[144*64];
  __shared__ float Zs[128];

  // ---- stage B (convert f32 KV/Ksum to hi/lo bf16, swizzled) ----
  const float* kvp = KV + (size_t)nh*DH*DH;
  for (int i = tid; i < DH*DH; i += 256) {
    const int m = i >> 6, d = i & 63;
    const float v = kvp[i];
    const short hi = f2bf_bits(v);
    bf16 hb; __builtin_memcpy(&hb, &hi, 2);
    const short lo = f2bf_bits(v - __bfloat162float(hb));
    Bs[bswz(m, d)]      = hi;
    Bs[bswz(64 + m, d)] = lo;
  }
  if (tid < 64) {
    const float v = Ksum[nh*DH + tid];
    const short hi = f2bf_bits(v);
    bf16 hb; __builtin_memcpy(&hb, &hi, 2);
    const short lo = f2bf_bits(v - __bfloat162float(hb));
    Bs[bswz(128, tid)] = hi;
    Bs[bswz(129, tid)] = lo;
  }
  for (int i = tid; i < 14*64; i += 256)
    Bs[(130 + (i >> 6))*64 + (i & 63)] = 0;
  __syncthreads();

  // ---- A fragments: direct global -> VGPR (each 16B seg read exactly once) ----
  const int l0 = lc * 128;
  const size_t qbase = ((size_t)(n*SEQLEN) + l0)*D_MODEL + h*DH;
  short8 afr[2][2];
  #pragma unroll
  for (int i = 0; i < 2; ++i)
    #pragma unroll
    for (int ks = 0; ks < 2; ++ks)
      afr[i][ks] = *(const short8*)(Ql + qbase +
                     (size_t)(wave*32 + i*16 + fr)*D_MODEL + ks*32 + quad*8);

  f32x4 acc[2][9] = {};
  #pragma unroll
  for (int ks = 0; ks < 2; ++ks) {
    #pragma unroll
    for (int j = 0; j < 9; ++j) {
      const int brow = j*16 + fr;
      const short8 bfr = *(const short8*)&Bs[brow*64 +
                            (((ks*4 + quad) ^ (fr & 7)) << 3)];
      #pragma unroll
      for (int i = 0; i < 2; ++i)
        acc[i][j] = __builtin_amdgcn_mfma_f32_16x16x32_bf16(afr[i][ks], bfr, acc[i][j], 0, 0, 0);
    }
  }

  // ---- denominators: Z[row] = 1/(P[row,128]+P[row,129]+eps) ----
  #pragma unroll
  for (int i = 0; i < 2; ++i) {
    #pragma unroll
    for (int r2 = 0; r2 < 4; ++r2) {
      const float v = acc[i][8][r2];
      const float vp = v + __shfl_xor(v, 1, 64);   // fr0 (hi) + fr1 (lo)
      if (fr == 0) Zs[wave*32 + i*16 + quad*4 + r2] = 1.0f / (vp + EPSV);
    }
  }
  __syncthreads();

  // ---- scale + store ----
  #pragma unroll
  for (int i = 0; i < 2; ++i) {
    #pragma unroll
    for (int r2 = 0; r2 < 4; ++r2) {
      const int rloc = wave*32 + i*16 + quad*4 + r2;
      const float z = Zs[rloc];
      #pragma unroll
      for (int j = 0; j < 4; ++j) {
        const float num = acc[i][j][r2] + acc[i][4 + j][r2];
        Vl[qbase + (size_t)rloc*D_MODEL + j*16 + fr] = __float2bfloat16(num * z);
      }
    }
  }
}

// ---------------- launch ----------------
extern "C" void kernel_launch(void* const* d_in, const int* in_sizes, int n_in,
                              void* d_out, int out_size, void* d_ws, size_t ws_size,
                              hipStream_t stream) {
  const float* q  = (const float*)d_in[0];
  const float* k  = (const float*)d_in[1];
  const float* v  = (const float*)d_in[2];
  const float* Wq = (const float*)d_in[3];
  const float* bq = (const float*)d_in[4];
  const float* Wk = (const float*)d_in[5];
  const float* bk = (const float*)d_in[6];
  const float* Wv = (const float*)d_in[7];
  const float* bv = (const float*)d_in[8];
  const float* Wo = (const float*)d_in[9];
  const float* bo = (const float*)d_in[10];
  float* out = (float*)d_out;

  bf16* WqT = (bf16*)d_ws;
  bf16* WkT = WqT + (size_t)D_MODEL*D_MODEL;
  bf16* WvT = WkT + (size_t)D_MODEL*D_MODEL;
  bf16* WoT = WvT + (size_t)D_MODEL*D_MODEL;
  bf16* Xb  = WoT + (size_t)D_MODEL*D_MODEL;   // 32 MB staging, reused q->k->v
  bf16* Ql  = Xb  + (size_t)MROWS*D_MODEL;
  bf16* Kl  = Ql  + (size_t)MROWS*D_MODEL;
  bf16* Vb  = Kl  + (size_t)MROWS*D_MODEL;
  bf16* Vl  = Kl;                              // reuse: K_lin dead after kv_kernel
  float* KV = (float*)(Vb + (size_t)MROWS*D_MODEL);
  float* Ks = KV + (size_t)NBATCH*NHEADS*DH*DH;

  hipMemsetAsync(KV, 0, ((size_t)NBATCH*NHEADS*DH*DH + NBATCH*NHEADS*DH)*sizeof(float), stream);

  transpose4<<<dim3(32,32,4), dim3(32,32,1), 0, stream>>>(Wq,Wk,Wv,Wo, WqT,WkT,WvT,WoT);

  const int nconv4 = MROWS*D_MODEL/4;
  dim3 gb(256), gg(D_MODEL/128, MROWS/128);    // (8, 128)

  cvt_bf16<<<nconv4/256, 256, 0, stream>>>(q, Xb);
  gemm_bias_act<1,bf16><<<gg, gb, 0, stream>>>(Xb, WqT, bq, Ql, MROWS, D_MODEL, D_MODEL);
  cvt_bf16<<<nconv4/256, 256, 0, stream>>>(k, Xb);
  gemm_bias_act<1,bf16><<<gg, gb, 0, stream>>>(Xb, WkT, bk, Kl, MROWS, D_MODEL, D_MODEL);
  cvt_bf16<<<nconv4/256, 256, 0, stream>>>(v, Xb);
  gemm_bias_act<0,bf16><<<gg, gb, 0, stream>>>(Xb, WvT, bv, Vb, MROWS, D_MODEL, D_MODEL);

  kv_kernel<<<dim3(NBATCH*NHEADS*KV_SPLIT), dim3(256), 0, stream>>>(Kl, Vb, KV, Ks);
  vlin_kernel<<<dim3(SEQLEN/128, NBATCH*NHEADS), dim3(256), 0, stream>>>(Ql, KV, Ks, Vl);

  gemm_bias_act<0,float><<<gg, gb, 0, stream>>>(Vl, WoT, bo, out, MROWS, D_MODEL, D_MODEL);
}

// Round 4
// 491.729 us; speedup vs baseline: 1.6101x; 1.2012x over previous
//
#include <hip/hip_runtime.h>
#include <hip/hip_bf16.h>
#include <stdint.h>

#define D_MODEL 1024
#define NHEADS  16
#define DH      64
#define NBATCH  4
#define SEQLEN  4096
#define MROWS   (NBATCH*SEQLEN)   // 16384
#define EPSV    1e-10f

typedef __hip_bfloat16 bf16;
typedef unsigned short ushort_t;
typedef __attribute__((ext_vector_type(8))) short short8;   // 8 bf16 (4 VGPRs)
typedef __attribute__((ext_vector_type(4))) float f32x4;

struct __align__(8) bf16x4s { bf16 a, b, c, d; };

__device__ __forceinline__ void async_copy16(void* lds, const void* g) {
  __builtin_amdgcn_global_load_lds(
      (const __attribute__((address_space(1))) unsigned int*)(uintptr_t)g,
      (__attribute__((address_space(3))) unsigned int*)(uintptr_t)lds,
      16, 0, 0);
}

__device__ __forceinline__ short f2bf_bits(float v) {
  bf16 b = __float2bfloat16(v);
  short s; __builtin_memcpy(&s, &b, 2); return s;
}
__device__ __forceinline__ float bfbits_to_f(ushort_t u) {
  return __uint_as_float(((unsigned int)u) << 16);
}

// ---------------- f32 -> bf16 conversion (vectorized, exact grid) ----------------
__global__ __launch_bounds__(256)
void cvt_bf16(const float* __restrict__ s, bf16* __restrict__ d) {
  const int i = blockIdx.x * 256 + threadIdx.x;
  const f32x4 v = ((const f32x4*)s)[i];
  bf16x4s o;
  o.a = __float2bfloat16(v[0]);
  o.b = __float2bfloat16(v[1]);
  o.c = __float2bfloat16(v[2]);
  o.d = __float2bfloat16(v[3]);
  ((bf16x4s*)d)[i] = o;
}

// ---------------- weight transpose + cvt (W[K,N] f32 -> WT[N,K] bf16) ----------------
__global__ void transpose4(const float* __restrict__ s0, const float* __restrict__ s1,
                           const float* __restrict__ s2, const float* __restrict__ s3,
                           bf16* __restrict__ d0, bf16* __restrict__ d1,
                           bf16* __restrict__ d2, bf16* __restrict__ d3) {
  const float* s; bf16* d;
  switch (blockIdx.z) {
    case 0: s = s0; d = d0; break;
    case 1: s = s1; d = d1; break;
    case 2: s = s2; d = d2; break;
    default: s = s3; d = d3; break;
  }
  __shared__ float tile[32][33];
  int x = blockIdx.x*32 + threadIdx.x;
  int y = blockIdx.y*32 + threadIdx.y;
  tile[threadIdx.y][threadIdx.x] = s[(size_t)y*D_MODEL + x];
  __syncthreads();
  int xo = blockIdx.y*32 + threadIdx.x;
  int yo = blockIdx.x*32 + threadIdx.y;
  d[(size_t)yo*D_MODEL + xo] = __float2bfloat16(tile[threadIdx.x][threadIdx.y]);
}

// ---------------- GEMM: C[M,N] = act(A[M,K] @ BT[N,K]^T + bias) ----------------
// 128x256 tile, BK=32, 4 waves x (4x8) 16x16x32 MFMA tiles.
// 512 blocks at 2 blocks/CU = exactly one residency round (no tail).
__device__ __forceinline__ void storeC(float* p, float v) { *p = v; }
__device__ __forceinline__ void storeC(bf16*  p, float v) { *p = __float2bfloat16(v); }

template<int ACT, typename CT>
__global__ __launch_bounds__(256, 2)
void gemm_bias_act(const bf16* __restrict__ A, const bf16* __restrict__ BT,
                   const float* __restrict__ bias, CT* __restrict__ C,
                   int M, int N, int K) {
  __shared__ __align__(16) short Asm[128*32];
  __shared__ __align__(16) short Bsm[256*32];
  const int tid  = threadIdx.x;
  const int wave = tid >> 6;
  const int lane = tid & 63;
  const int m0 = blockIdx.y * 128;
  const int n0 = blockIdx.x * 256;
  const int wr = wave >> 1, wc = wave & 1;
  const int srow = tid >> 2;              // 0..63 staging row within a 64-row round
  const int scol = (tid & 3) * 8;         // 8 bf16 = 16 B
  const int fr   = lane & 15;
  const int quad = lane >> 4;

  f32x4 acc[4][8] = {};

  for (int k0 = 0; k0 < K; k0 += 32) {
    __syncthreads();
    #pragma unroll
    for (int r = 0; r < 2; ++r) {
      const int row = r*64 + srow;
      async_copy16(&Asm[row*32 + scol], A + (size_t)(m0+row)*K + k0 + scol);
    }
    #pragma unroll
    for (int r = 0; r < 4; ++r) {
      const int row = r*64 + srow;
      async_copy16(&Bsm[row*32 + scol], BT + (size_t)(n0+row)*K + k0 + scol);
    }
    __syncthreads();
    short8 afr[4], bfr[8];
    #pragma unroll
    for (int i = 0; i < 4; ++i)
      afr[i] = *(const short8*)&Asm[(wr*64 + i*16 + fr)*32 + quad*8];
    #pragma unroll
    for (int j = 0; j < 8; ++j)
      bfr[j] = *(const short8*)&Bsm[(wc*128 + j*16 + fr)*32 + quad*8];
    #pragma unroll
    for (int i = 0; i < 4; ++i)
      #pragma unroll
      for (int j = 0; j < 8; ++j)
        acc[i][j] = __builtin_amdgcn_mfma_f32_16x16x32_bf16(afr[i], bfr[j], acc[i][j], 0, 0, 0);
  }

  // C/D layout: col(n)=lane&15, row(m)=quad*4+reg  [measured m89/m91]
  #pragma unroll
  for (int j = 0; j < 8; ++j) {
    const int gn = n0 + wc*128 + j*16 + fr;
    const float bv = bias[gn];
    #pragma unroll
    for (int i = 0; i < 4; ++i) {
      const int gm = m0 + wr*64 + i*16 + quad*4;
      #pragma unroll
      for (int r2 = 0; r2 < 4; ++r2) {
        float v = acc[i][j][r2] + bv;
        if (ACT) v = (v > 0.f) ? (v + 1.f) : __expf(v);   // elu(x)+1
        storeC(&C[(size_t)(gm + r2)*N + gn], v);
      }
    }
  }
}

// ---------------- KV + K_sum partials via MFMA ----------------
// Per (n,h): KV[m][d] = sum_s V[s,m]*K[s,d]  (M=N=64, K=4096, split 16)
// Stage transposed tiles Kt[d][s],Vt[m][s] (64x64) with s-block XOR swizzle.
#define KV_SPLIT 16
__global__ __launch_bounds__(256)
void kv_kernel(const bf16* __restrict__ Kl, const bf16* __restrict__ V,
               float* __restrict__ KVp, float* __restrict__ Ksp) {
  const int b  = blockIdx.x;
  const int sp = b & (KV_SPLIT-1);
  const int nh = b >> 4;
  const int h = nh & (NHEADS-1), n = nh >> 4;
  const int tid = threadIdx.x;
  const int wave = tid >> 6, lane = tid & 63;
  const int fr = lane & 15, quad = lane >> 4;
  const int d = lane;                     // staging channel 0..63

  __shared__ __align__(16) short Kt[64*64];
  __shared__ __align__(16) short Vt[64*64];
  __shared__ float Ksl[4][64];

  const ushort_t* Kg = (const ushort_t*)Kl;
  const ushort_t* Vg = (const ushort_t*)V;

  f32x4 acc[4] = {};
  float ksacc = 0.f;
  const int s_base = sp * (SEQLEN / KV_SPLIT);   // 256 s-rows per block

  for (int c0 = 0; c0 < 256; c0 += 64) {
    __syncthreads();
    #pragma unroll
    for (int i = 0; i < 2; ++i) {
      const int s8 = wave*2 + i;          // s-block 0..7
      const size_t gbase = ((size_t)(n*SEQLEN + s_base + c0 + s8*8))*D_MODEL + h*DH + d;
      short8 pk, pv;
      #pragma unroll
      for (int e = 0; e < 8; ++e) {
        const ushort_t ku = Kg[gbase + (size_t)e*D_MODEL];   // 64 lanes x 2B contiguous
        const ushort_t vu = Vg[gbase + (size_t)e*D_MODEL];
        pk[e] = (short)ku;
        pv[e] = (short)vu;
        ksacc += bfbits_to_f(ku);
      }
      const int wofs = d*64 + ((s8 ^ (d & 7)) << 3);   // swizzled: 2-way-free b128 write
      *(short8*)&Kt[wofs] = pk;
      *(short8*)&Vt[wofs] = pv;
    }
    __syncthreads();
    #pragma unroll
    for (int k0 = 0; k0 < 2; ++k0) {
      const int s8a = k0*4 + quad;
      const int arow = wave*16 + fr;      // m-strip per wave
      const short8 afr = *(const short8*)&Vt[arow*64 + ((s8a ^ (arow & 7)) << 3)];
      #pragma unroll
      for (int j = 0; j < 4; ++j) {
        const int brow = j*16 + fr;
        const short8 bfr = *(const short8*)&Kt[brow*64 + ((s8a ^ (brow & 7)) << 3)];
        acc[j] = __builtin_amdgcn_mfma_f32_16x16x32_bf16(afr, bfr, acc[j], 0, 0, 0);
      }
    }
  }

  // Ksum partial: each thread covered (d = lane, s-blocks wave*2..wave*2+1) fully
  Ksl[wave][d] = ksacc;
  __syncthreads();
  if (tid < 64)
    Ksp[b*64 + tid] = Ksl[0][tid] + Ksl[1][tid] + Ksl[2][tid] + Ksl[3][tid];

  // KV partial: m = wave*16 + quad*4 + r, col d = j*16 + fr
  float* outp = KVp + (size_t)b*4096;
  #pragma unroll
  for (int j = 0; j < 4; ++j)
    #pragma unroll
    for (int r = 0; r < 4; ++r)
      outp[(wave*16 + quad*4 + r)*64 + j*16 + fr] = acc[j][r];
}

// ---------------- reduce 16 partials -> KV, Ksum ----------------
__global__ __launch_bounds__(256)
void kv_reduce(const float* __restrict__ KVp, const float* __restrict__ Ksp,
               float* __restrict__ KV, float* __restrict__ Ksum) {
  const int c  = blockIdx.x;    // 0..3
  const int nh = blockIdx.y;    // 0..63
  const int e = c*1024 + threadIdx.x*4;
  f32x4 s = {};
  #pragma unroll
  for (int sp = 0; sp < KV_SPLIT; ++sp)
    s += *(const f32x4*)(KVp + ((size_t)(nh*KV_SPLIT + sp))*4096 + e);
  *(f32x4*)(KV + (size_t)nh*4096 + e) = s;
  if (c == 0 && threadIdx.x < 64) {
    float ks = 0.f;
    #pragma unroll
    for (int sp = 0; sp < KV_SPLIT; ++sp)
      ks += Ksp[(nh*KV_SPLIT + sp)*64 + threadIdx.x];
    Ksum[nh*64 + threadIdx.x] = ks;
  }
}

// ---------------- V_lin = Z * (Q_lin . KV)  — MFMA batched GEMM ----------------
__device__ __forceinline__ int bswz(int row, int d) {   // XOR-swizzled LDS index
  return row*64 + ((((d >> 3) ^ (row & 7)) << 3) | (d & 7));
}

__global__ __launch_bounds__(256)
void vlin_kernel(const bf16* __restrict__ Ql, const float* __restrict__ KV,
                 const float* __restrict__ Ksum, bf16* __restrict__ Vl) {
  const int lc = blockIdx.x;            // l-chunk of 128 rows (32 total)
  const int nh = blockIdx.y;            // n*NHEADS + h
  const int h = nh & (NHEADS-1), n = nh >> 4;
  const int tid = threadIdx.x, wave = tid >> 6, lane = tid & 63;
  const int fr = lane & 15, quad = lane >> 4;

  __shared__ __align__(16) short Bs[144*64];
  __shared__ float Zs[128];

  // ---- stage B (f32 KV/Ksum -> hi/lo bf16, swizzled) ----
  const float* kvp = KV + (size_t)nh*DH*DH;
  for (int i = tid; i < DH*DH; i += 256) {
    const int m = i >> 6, d = i & 63;
    const float v = kvp[i];
    const short hi = f2bf_bits(v);
    bf16 hb; __builtin_memcpy(&hb, &hi, 2);
    const short lo = f2bf_bits(v - __bfloat162float(hb));
    Bs[bswz(m, d)]      = hi;
    Bs[bswz(64 + m, d)] = lo;
  }
  if (tid < 64) {
    const float v = Ksum[nh*DH + tid];
    const short hi = f2bf_bits(v);
    bf16 hb; __builtin_memcpy(&hb, &hi, 2);
    const short lo = f2bf_bits(v - __bfloat162float(hb));
    Bs[bswz(128, tid)] = hi;
    Bs[bswz(129, tid)] = lo;
  }
  for (int i = tid; i < 14*64; i += 256)
    Bs[(130 + (i >> 6))*64 + (i & 63)] = 0;
  __syncthreads();

  // ---- A fragments: direct global -> VGPR ----
  const int l0 = lc * 128;
  const size_t qbase = ((size_t)(n*SEQLEN) + l0)*D_MODEL + h*DH;
  short8 afr[2][2];
  #pragma unroll
  for (int i = 0; i < 2; ++i)
    #pragma unroll
    for (int ks = 0; ks < 2; ++ks)
      afr[i][ks] = *(const short8*)(Ql + qbase +
                     (size_t)(wave*32 + i*16 + fr)*D_MODEL + ks*32 + quad*8);

  f32x4 acc[2][9] = {};
  #pragma unroll
  for (int ks = 0; ks < 2; ++ks) {
    #pragma unroll
    for (int j = 0; j < 9; ++j) {
      const int brow = j*16 + fr;
      const short8 bfr = *(const short8*)&Bs[brow*64 +
                            (((ks*4 + quad) ^ (fr & 7)) << 3)];
      #pragma unroll
      for (int i = 0; i < 2; ++i)
        acc[i][j] = __builtin_amdgcn_mfma_f32_16x16x32_bf16(afr[i][ks], bfr, acc[i][j], 0, 0, 0);
    }
  }

  // ---- Z[row] = 1/(P[row,128]+P[row,129]+eps) ----
  #pragma unroll
  for (int i = 0; i < 2; ++i) {
    #pragma unroll
    for (int r2 = 0; r2 < 4; ++r2) {
      const float v = acc[i][8][r2];
      const float vp = v + __shfl_xor(v, 1, 64);
      if (fr == 0) Zs[wave*32 + i*16 + quad*4 + r2] = 1.0f / (vp + EPSV);
    }
  }
  __syncthreads();

  // ---- scale + store ----
  #pragma unroll
  for (int i = 0; i < 2; ++i) {
    #pragma unroll
    for (int r2 = 0; r2 < 4; ++r2) {
      const int rloc = wave*32 + i*16 + quad*4 + r2;
      const float z = Zs[rloc];
      #pragma unroll
      for (int j = 0; j < 4; ++j) {
        const float num = acc[i][j][r2] + acc[i][4 + j][r2];
        Vl[qbase + (size_t)rloc*D_MODEL + j*16 + fr] = __float2bfloat16(num * z);
      }
    }
  }
}

// ---------------- launch ----------------
extern "C" void kernel_launch(void* const* d_in, const int* in_sizes, int n_in,
                              void* d_out, int out_size, void* d_ws, size_t ws_size,
                              hipStream_t stream) {
  const float* q  = (const float*)d_in[0];
  const float* k  = (const float*)d_in[1];
  const float* v  = (const float*)d_in[2];
  const float* Wq = (const float*)d_in[3];
  const float* bq = (const float*)d_in[4];
  const float* Wk = (const float*)d_in[5];
  const float* bk = (const float*)d_in[6];
  const float* Wv = (const float*)d_in[7];
  const float* bv = (const float*)d_in[8];
  const float* Wo = (const float*)d_in[9];
  const float* bo = (const float*)d_in[10];
  float* out = (float*)d_out;

  bf16* WqT = (bf16*)d_ws;
  bf16* WkT = WqT + (size_t)D_MODEL*D_MODEL;
  bf16* WvT = WkT + (size_t)D_MODEL*D_MODEL;
  bf16* WoT = WvT + (size_t)D_MODEL*D_MODEL;
  bf16* Xb  = WoT + (size_t)D_MODEL*D_MODEL;   // 32 MB staging, reused q->k->v
  bf16* Ql  = Xb  + (size_t)MROWS*D_MODEL;
  bf16* Kl  = Ql  + (size_t)MROWS*D_MODEL;
  bf16* Vb  = Kl  + (size_t)MROWS*D_MODEL;
  bf16* Vl  = Kl;                              // reuse: K_lin dead after kv_kernel
  float* KV = (float*)(Vb + (size_t)MROWS*D_MODEL);
  float* Ks = KV + (size_t)NBATCH*NHEADS*DH*DH;
  // kv partials overlay the dead Xb region (dead after the V-projection GEMM)
  float* KVp = (float*)Xb;                                   // 16 MB
  float* Ksp = KVp + (size_t)NBATCH*NHEADS*KV_SPLIT*DH*DH;   // 256 KB

  transpose4<<<dim3(32,32,4), dim3(32,32,1), 0, stream>>>(Wq,Wk,Wv,Wo, WqT,WkT,WvT,WoT);

  const int nconv4 = MROWS*D_MODEL/4;
  dim3 gb(256), gg(D_MODEL/256, MROWS/128);    // (4, 128) = 512 blocks

  cvt_bf16<<<nconv4/256, 256, 0, stream>>>(q, Xb);
  gemm_bias_act<1,bf16><<<gg, gb, 0, stream>>>(Xb, WqT, bq, Ql, MROWS, D_MODEL, D_MODEL);
  cvt_bf16<<<nconv4/256, 256, 0, stream>>>(k, Xb);
  gemm_bias_act<1,bf16><<<gg, gb, 0, stream>>>(Xb, WkT, bk, Kl, MROWS, D_MODEL, D_MODEL);
  cvt_bf16<<<nconv4/256, 256, 0, stream>>>(v, Xb);
  gemm_bias_act<0,bf16><<<gg, gb, 0, stream>>>(Xb, WvT, bv, Vb, MROWS, D_MODEL, D_MODEL);

  kv_kernel<<<dim3(NBATCH*NHEADS*KV_SPLIT), dim3(256), 0, stream>>>(Kl, Vb, KVp, Ksp);
  kv_reduce<<<dim3(4, NBATCH*NHEADS), dim3(256), 0, stream>>>(KVp, Ksp, KV, Ks);
  vlin_kernel<<<dim3(SEQLEN/128, NBATCH*NHEADS), dim3(256), 0, stream>>>(Ql, KV, Ks, Vl);

  gemm_bias_act<0,float><<<gg, gb, 0, stream>>>(Vl, WoT, bo, out, MROWS, D_MODEL, D_MODEL);
}